// Round 4
// baseline (40217.343 us; speedup 1.0000x reference)
//
#include <hip/hip_runtime.h>
#include <hip/hip_bf16.h>

#if __has_builtin(__builtin_amdgcn_exp2f)
#define EXP2F(x) __builtin_amdgcn_exp2f(x)
#else
#define EXP2F(x) exp2f(x)
#endif
#if __has_builtin(__builtin_amdgcn_rcpf)
#define RCPF(x) __builtin_amdgcn_rcpf(x)
#else
#define RCPF(x) (1.0f/(x))
#endif

typedef _Float16 h2f16 __attribute__((ext_vector_type(2)));

namespace {
constexpr int   kT   = 127;
constexpr int   kE   = 128;
constexpr int   kB   = 4096;
constexpr int   kNWG = 512;
constexpr int   kBPW = kB / kNWG;          // 8 batch elements per workgroup
constexpr float kLog2e = 1.4426950408889634f;
constexpr float kK2    = 2.8853900817779268f;   // 2*log2(e)
constexpr int   kSmemBytes = 74048;

__device__ __forceinline__ unsigned int packf16(float a, float b) {
  h2f16 h = { (_Float16)a, (_Float16)b };
  return __builtin_bit_cast(unsigned int, h);
}
__device__ __forceinline__ float lo16f(unsigned int u) {
  h2f16 h = __builtin_bit_cast(h2f16, u); return (float)h.x;
}
__device__ __forceinline__ float hi16f(unsigned int u) {
  h2f16 h = __builtin_bit_cast(h2f16, u); return (float)h.y;
}

#if __has_builtin(__builtin_amdgcn_fdot2)
__device__ __forceinline__ float fdot2f(unsigned int a, unsigned int b, float c) {
  return __builtin_amdgcn_fdot2(__builtin_bit_cast(h2f16, a),
                                __builtin_bit_cast(h2f16, b), c, false);
}
#else
__device__ __forceinline__ float fdot2f(unsigned int a, unsigned int b, float c) {
  h2f16 ha = __builtin_bit_cast(h2f16, a), hb = __builtin_bit_cast(h2f16, b);
  return c + (float)ha.x * (float)hb.x + (float)ha.y * (float)hb.y;
}
#endif

__device__ __forceinline__ float redsum64(float a) {
#pragma unroll
  for (int m = 1; m < 64; m <<= 1) a += __shfl_xor(a, m, 64);
  return a;
}

// 256 threads, 4 waves, one batch element at a time, 2 blocks/CU.
__global__ __launch_bounds__(256, 2) void decoder_kernel(
    const float* __restrict__ Xg,    // [B,127,128]
    const float* __restrict__ yh,    // [B,127]
    const float* __restrict__ vdw,   // [128]
    const float* __restrict__ vdb,   // [1]
    const float* __restrict__ Wdhs,  // [128,256]
    const float* __restrict__ Wdhsb, // [128]
    const float* __restrict__ Udw,   // [128,128]
    const float* __restrict__ Udb,   // [128]
    const float* __restrict__ ww,    // [129]
    const float* __restrict__ wb,    // [1]
    const float* __restrict__ Wih,   // [512]
    const float* __restrict__ Whh,   // [512,128]
    const float* __restrict__ bih,   // [512]
    const float* __restrict__ bhh,   // [512]
    const float* __restrict__ fcww,  // [256]
    const float* __restrict__ fcb,   // [1]
    float* __restrict__ out)         // [B]
{
  extern __shared__ char smem[];
  unsigned int* u2u  = (unsigned int*)smem;            // [128 t][64] f16-pairs, K2-prescaled U, 8-elem-chunk XOR swizzle
  unsigned int* xbT  = (unsigned int*)(smem + 32768);  // [128 e][64 t2] f16 pairs (x[2t2],x[2t2+1]), t2 ^ (e&63)
  float* hl    = (float*)(smem + 65536);  // [128] h fp32 (final fc)
  float* p2    = hl    + 128;             // [128] K2*proj
  float* sc    = p2    + 128;             // [128] scores
  float* beta  = sc    + 128;             // [128] fp32 softmax
  float* ctxl  = beta  + 128;             // [128] final ctx fp32
  float* wwl   = ctxl  + 128;             // [132] w_w(129) + w_b at [129]
  float* fcw   = wwl   + 132;             // [256]
  float* wdb_l = fcw   + 256;             // [128]
  float* yrow  = wdb_l + 128;             // [128]
  float* v2l   = yrow  + 128;             // [128] -2*v_d
  float* ypart = v2l   + 128;             // [8]   per-wave y-tilde partials
  float* act   = ypart + 8;               // [512] gate activations
  unsigned int* hc2   = (unsigned int*)(act + 512);   // [128] f16 pairs: h2[64], c2[64]
  unsigned int* beta2 = hc2 + 128;                    // [64]  f16 pairs of beta

  const int t    = threadIdx.x;          // 0..255
  const int prow = t >> 1;               // proj row / score row / ctx e / U2 row
  const int half = t & 1;                // half selector
  const int g0   = t;                    // gate row 0 (i or f)
  const int g1   = t + 256;              // gate row 1 (g~ or o)

  // ---- persistent per-thread weights in VGPRs (~196, pinned) ----
  unsigned int whh0[64], whh1[64], wdp[64];
#pragma unroll
  for (int p = 0; p < 64; ++p)
    whh0[p] = packf16(Whh[g0 * 128 + 2 * p], Whh[g0 * 128 + 2 * p + 1]);
#pragma unroll
  for (int p = 0; p < 64; ++p)
    whh1[p] = packf16(Whh[g1 * 128 + 2 * p], Whh[g1 * 128 + 2 * p + 1]);
#pragma unroll
  for (int p = 0; p < 64; ++p)
    wdp[p] = packf16(Wdhs[prow * 256 + half * 128 + 2 * p],
                     Wdhs[prow * 256 + half * 128 + 2 * p + 1]);
  float bihh0 = bih[g0] + bhh[g0];
  float bihh1 = bih[g1] + bhh[g1];
  float wih0  = Wih[g0];
  float wih1  = Wih[g1];
#pragma unroll
  for (int p = 0; p < 64; ++p) asm volatile("" : "+v"(whh0[p]));
#pragma unroll
  for (int p = 0; p < 64; ++p) asm volatile("" : "+v"(whh1[p]));
#pragma unroll
  for (int p = 0; p < 64; ++p) asm volatile("" : "+v"(wdp[p]));
  asm volatile("" : "+v"(bihh0));
  asm volatile("" : "+v"(bihh1));
  asm volatile("" : "+v"(wih0));
  asm volatile("" : "+v"(wih1));

  // ---- one-time constants to LDS ----
  if (t < 129) wwl[t] = ww[t];
  if (t == 0)  wwl[129] = wb[0];
  fcw[t] = fcww[t];
  if (t < 128) { wdb_l[t] = Wdhsb[t]; v2l[t] = -2.0f * vdw[t]; }

  for (int bi = 0; bi < kBPW; ++bi) {
    const int b = blockIdx.x * kBPW + bi;
    const float* Xb = Xg + (size_t)b * (kT * kE);
    float creg = 0.0f;
    __syncthreads();   // previous batch done with LDS

    // ---- stage xbT (f16 t-pairs, swizzled), yrow, zero h2/c2 ----
    {
      const int e = t & 127, t2g = t >> 7;
      for (int t2 = t2g; t2 < 64; t2 += 2) {
        const float a  = Xb[(2 * t2) * kE + e];
        const float bq = (t2 == 63) ? 0.0f : Xb[(2 * t2 + 1) * kE + e];
        xbT[e * 64 + (t2 ^ (e & 63))] = packf16(a, bq);
      }
    }
    if (t < kT)  yrow[t] = yh[b * kT + t];
    if (t < 128) hc2[t] = 0u;

    // ---- U2 = K2*(X @ Udw^T + Udb), f16 pairs, swizzled; fp32 inputs ----
    if (prow < kT) {
      const float* Xrow = Xb + prow * kE;
      const int ts7 = prow & 7;
#pragma unroll
      for (int jh = 0; jh < 8; ++jh) {
        const int eb = half * 64 + jh * 8;   // output base
        float acc[8];
#pragma unroll
        for (int j = 0; j < 8; ++j) acc[j] = 0.0f;
        for (int k0 = 0; k0 < kE; k0 += 4) {
          const float4 xq = *(const float4*)&Xrow[k0];
#pragma unroll
          for (int j = 0; j < 8; ++j) {
            const float4 wq = *(const float4*)&Udw[(eb + j) * kE + k0];
            acc[j] += xq.x * wq.x + xq.y * wq.y + xq.z * wq.z + xq.w * wq.w;
          }
        }
        const int c = half * 8 + jh;         // 8-elem chunk index
        uint4 st;
        st.x = packf16(kK2 * (acc[0] + Udb[eb + 0]), kK2 * (acc[1] + Udb[eb + 1]));
        st.y = packf16(kK2 * (acc[2] + Udb[eb + 2]), kK2 * (acc[3] + Udb[eb + 3]));
        st.z = packf16(kK2 * (acc[4] + Udb[eb + 4]), kK2 * (acc[5] + Udb[eb + 5]));
        st.w = packf16(kK2 * (acc[6] + Udb[eb + 6]), kK2 * (acc[7] + Udb[eb + 7]));
        *(uint4*)&u2u[prow * 64 + ((c ^ ts7) << 2)] = st;
      }
    }
    __syncthreads();

    // ================= 127 recurrent steps =================
    for (int s = 0; s < kT; ++s) {
      // P1: both gate rows (kept in regs) + proj half-row; h/c from LDS broadcast
      float gacc0 = 0.0f, gacc1 = 0.0f;
#pragma unroll
      for (int q = 0; q < 16; ++q) {
        const uint4 h4 = *(const uint4*)&hc2[q * 4];
        gacc0 = fdot2f(whh0[q*4+0], h4.x, gacc0);
        gacc0 = fdot2f(whh0[q*4+1], h4.y, gacc0);
        gacc0 = fdot2f(whh0[q*4+2], h4.z, gacc0);
        gacc0 = fdot2f(whh0[q*4+3], h4.w, gacc0);
        gacc1 = fdot2f(whh1[q*4+0], h4.x, gacc1);
        gacc1 = fdot2f(whh1[q*4+1], h4.y, gacc1);
        gacc1 = fdot2f(whh1[q*4+2], h4.z, gacc1);
        gacc1 = fdot2f(whh1[q*4+3], h4.w, gacc1);
      }
      float pacc = 0.0f;
#pragma unroll
      for (int q = 0; q < 16; ++q) {
        const uint4 h4 = *(const uint4*)&hc2[half * 64 + q * 4];
        pacc = fdot2f(wdp[q*4+0], h4.x, pacc);
        pacc = fdot2f(wdp[q*4+1], h4.y, pacc);
        pacc = fdot2f(wdp[q*4+2], h4.z, pacc);
        pacc = fdot2f(wdp[q*4+3], h4.w, pacc);
      }
      const float po = __shfl_xor(pacc, 1, 64);
      if (half == 0) p2[prow] = kK2 * (pacc + po + wdb_l[prow]);
      __syncthreads();  // B1

      // P2: scores[t] ∝ -2*sum_e v[e]*rcp(1+exp2(p2[e]+U2[t][e]))  (softmax-shift-invariant)
      if (prow < kT) {
        const int ro = prow * 64, ts7 = prow & 7;
        float sacc = 0.0f;
#pragma unroll
        for (int cc = 0; cc < 8; ++cc) {
          const int c = half * 8 + cc;
          const uint4 uq = *(const uint4*)&u2u[ro + ((c ^ ts7) << 2)];
          const float4 pa = *(const float4*)&p2[c * 8];
          const float4 pb = *(const float4*)&p2[c * 8 + 4];
          const float4 va = *(const float4*)&v2l[c * 8];
          const float4 vb = *(const float4*)&v2l[c * 8 + 4];
          const unsigned int uu[4] = {uq.x, uq.y, uq.z, uq.w};
          const float pv[8] = {pa.x, pa.y, pa.z, pa.w, pb.x, pb.y, pb.z, pb.w};
          const float vv[8] = {va.x, va.y, va.z, va.w, vb.x, vb.y, vb.z, vb.w};
#pragma unroll
          for (int q = 0; q < 4; ++q) {
            const float x0 = lo16f(uu[q]) + pv[2*q];
            const float x1 = hi16f(uu[q]) + pv[2*q+1];
            sacc += vv[2*q]   * RCPF(1.0f + EXP2F(x0));
            sacc += vv[2*q+1] * RCPF(1.0f + EXP2F(x1));
          }
        }
        const float so = __shfl_xor(sacc, 1, 64);
        if (half == 0) sc[prow] = sacc + so;
      }
      __syncthreads();  // B2

      // P3: softmax over t (wave 0 only; no max pass — scores bounded)
      if (t < 64) {
        const float e0  = EXP2F(sc[t] * kLog2e);
        const float e1x = (t + 64 < kT) ? EXP2F(sc[t + 64] * kLog2e) : 0.0f;
        float sum = e0 + e1x;
        sum = redsum64(sum);
        const float rs = RCPF(sum);
        const float b0 = e0 * rs, b1 = e1x * rs;
        beta[t]      = b0;
        beta[t + 64] = b1;               // beta[127] = 0
        const float bo0 = __shfl_xor(b0, 1, 64);
        const float bo1 = __shfl_xor(b1, 1, 64);
        if ((t & 1) == 0) {
          beta2[t >> 1]        = packf16(b0, bo0);
          beta2[32 + (t >> 1)] = packf16(b1, bo1);
        }
      }
      __syncthreads();  // B3

      // P4: ctx half-dots (2 lanes/e) + per-wave y_tilde partials
      {
        const int e = prow, em = e & 63;
        float cacc = 0.0f;
#pragma unroll
        for (int q = 0; q < 32; ++q) {
          const int t2 = half * 32 + q;
          cacc = fdot2f(beta2[t2], xbT[e * 64 + (t2 ^ em)], cacc);
        }
        float yp = redsum64(cacc * wwl[e]);
        if ((t & 63) == 0) ypart[t >> 6] = yp;
      }
      __syncthreads();  // B4

      // P5: y_tilde scalar + both gates + nonlinearities (gates never leave regs)
      {
        const float y_t = ypart[0] + ypart[1] + ypart[2] + ypart[3]
                        + wwl[128] * yrow[s] + wwl[129];
        const float ga = gacc0 + bihh0 + y_t * wih0;   // i or f: sigmoid
        const float gb = gacc1 + bihh1 + y_t * wih1;   // g~: tanh (t<128), o: sigmoid
        const float a0 = RCPF(1.0f + EXP2F(-ga * kLog2e));
        float a1;
        if (t < 128) a1 = 1.0f - 2.0f * RCPF(1.0f + EXP2F(gb * kK2));   // wave-uniform branch
        else         a1 = RCPF(1.0f + EXP2F(-gb * kLog2e));
        act[t]       = a0;
        act[256 + t] = a1;
      }
      __syncthreads();  // B5

      // P6: LSTM state update (lanes 0-127)
      if (t < 128) {
        const float i_g = act[t];
        const float f_g = act[128 + t];
        const float gg  = act[256 + t];
        const float o_g = act[384 + t];
        const float cn  = f_g * creg + i_g * gg;
        const float th  = 1.0f - 2.0f * RCPF(1.0f + EXP2F(cn * kK2));
        const float hn  = o_g * th;
        creg = cn;
        hl[t] = hn;
        const float ho = __shfl_xor(hn, 1, 64);
        const float co = __shfl_xor(cn, 1, 64);
        if ((t & 1) == 0) {
          hc2[t >> 1]        = packf16(hn, ho);
          hc2[64 + (t >> 1)] = packf16(cn, co);
        }
      }
      __syncthreads();  // B6
    }  // steps

    // ---- final ctx in fp32 from global X (protects the direct fc path) ----
    {
      const int e = prow;
      float cacc = 0.0f;
#pragma unroll
      for (int q = 0; q < 64; ++q) {
        const int tt = half * 64 + q;
        if (tt < kT) cacc += beta[tt] * Xb[tt * kE + e];
      }
      const float co = __shfl_xor(cacc, 1, 64);
      if (half == 0) ctxl[e] = cacc + co;
    }
    __syncthreads();
    if (t < 64) {
      float a = hl[t] * fcw[t] + hl[t + 64] * fcw[t + 64]
              + ctxl[t] * fcw[128 + t] + ctxl[t + 64] * fcw[192 + t];
      a = redsum64(a);
      if (t == 0) out[b] = a + fcb[0];
    }
  }  // batch loop
}
}  // namespace

extern "C" void kernel_launch(void* const* d_in, const int* in_sizes, int n_in,
                              void* d_out, int out_size, void* d_ws, size_t ws_size,
                              hipStream_t stream) {
  (void)in_sizes; (void)n_in; (void)d_ws; (void)ws_size; (void)out_size;
  const float* Xg    = (const float*)d_in[0];
  const float* yh    = (const float*)d_in[1];
  const float* vdw   = (const float*)d_in[2];
  const float* vdb   = (const float*)d_in[3];
  const float* Wdhs  = (const float*)d_in[4];
  const float* Wdhsb = (const float*)d_in[5];
  const float* Udw   = (const float*)d_in[6];
  const float* Udb   = (const float*)d_in[7];
  const float* ww    = (const float*)d_in[8];
  const float* wb    = (const float*)d_in[9];
  const float* Wih   = (const float*)d_in[10];
  const float* Whh   = (const float*)d_in[11];
  const float* bih   = (const float*)d_in[12];
  const float* bhh   = (const float*)d_in[13];
  const float* fcww  = (const float*)d_in[14];
  const float* fcb   = (const float*)d_in[15];
  float* out = (float*)d_out;

  hipFuncSetAttribute((const void*)decoder_kernel,
                      hipFuncAttributeMaxDynamicSharedMemorySize, kSmemBytes);
  decoder_kernel<<<dim3(kNWG), dim3(256), kSmemBytes, stream>>>(
      Xg, yh, vdw, vdb, Wdhs, Wdhsb, Udw, Udb, ww, wb,
      Wih, Whh, bih, bhh, fcww, fcb, out);
}

// Round 5
// 12043.916 us; speedup vs baseline: 3.3392x; 3.3392x over previous
//
#include <hip/hip_runtime.h>
#include <hip/hip_bf16.h>

#if __has_builtin(__builtin_amdgcn_exp2f)
#define EXP2F(x) __builtin_amdgcn_exp2f(x)
#else
#define EXP2F(x) exp2f(x)
#endif
#if __has_builtin(__builtin_amdgcn_rcpf)
#define RCPF(x) __builtin_amdgcn_rcpf(x)
#else
#define RCPF(x) (1.0f/(x))
#endif

typedef _Float16 h2f16 __attribute__((ext_vector_type(2)));

namespace {
constexpr int   kT   = 127;
constexpr int   kE   = 128;
constexpr int   kB   = 4096;
constexpr int   kNWG = 256;
constexpr int   kBPW = 16;                 // batches per workgroup (8 pairs)
constexpr float kLog2e = 1.4426950408889634f;
constexpr float kK2    = 2.8853900817779268f;   // 2*log2(e)
constexpr int   kSmemBytes = 153648;

__device__ __forceinline__ unsigned int packf16(float a, float b) {
  h2f16 h = { (_Float16)a, (_Float16)b };
  return __builtin_bit_cast(unsigned int, h);
}
__device__ __forceinline__ float lo16f(unsigned int u) {
  h2f16 h = __builtin_bit_cast(h2f16, u); return (float)h.x;
}
__device__ __forceinline__ float hi16f(unsigned int u) {
  h2f16 h = __builtin_bit_cast(h2f16, u); return (float)h.y;
}

#if __has_builtin(__builtin_amdgcn_fdot2)
__device__ __forceinline__ float fdot2f(unsigned int a, unsigned int b, float c) {
  return __builtin_amdgcn_fdot2(__builtin_bit_cast(h2f16, a),
                                __builtin_bit_cast(h2f16, b), c, false);
}
#else
__device__ __forceinline__ float fdot2f(unsigned int a, unsigned int b, float c) {
  h2f16 ha = __builtin_bit_cast(h2f16, a), hb = __builtin_bit_cast(h2f16, b);
  return c + (float)ha.x * (float)hb.x + (float)ha.y * (float)hb.y;
}
#endif

__device__ __forceinline__ float redsum64(float a) {
#pragma unroll
  for (int m = 1; m < 64; m <<= 1) a += __shfl_xor(a, m, 64);
  return a;
}

// 1024 threads, 16 waves, TWO batch elements processed together per block.
__global__ __launch_bounds__(1024, 4) void decoder_kernel(
    const float* __restrict__ Xg,    // [B,127,128]
    const float* __restrict__ yh,    // [B,127]
    const float* __restrict__ vdw,   // [128]
    const float* __restrict__ vdb,   // [1]
    const float* __restrict__ Wdhs,  // [128,256]
    const float* __restrict__ Wdhsb, // [128]
    const float* __restrict__ Udw,   // [128,128]
    const float* __restrict__ Udb,   // [128]
    const float* __restrict__ ww,    // [129]
    const float* __restrict__ wb,    // [1]
    const float* __restrict__ Wih,   // [512]
    const float* __restrict__ Whh,   // [512,128]
    const float* __restrict__ bih,   // [512]
    const float* __restrict__ bhh,   // [512]
    const float* __restrict__ fcww,  // [256]
    const float* __restrict__ fcb,   // [1]
    float* __restrict__ out)         // [B]
{
  extern __shared__ char smem[];
  unsigned int* u2u = (unsigned int*)smem;            // [2][128][64] f16-pairs, K2-prescaled U; 16B chunk c at c^(t&15)
  unsigned int* xbT = (unsigned int*)(smem + 65536);  // [2][128 e][64 t2] f16 (x[2t2],x[2t2+1]) at t2^(e&63); also Udw2 scratch
  float* hl   = (float*)(smem + 131072);  // [2][128] h fp32
  float* p2   = hl   + 256;               // [2][128]
  float* sc   = p2   + 256;               // [2][128]
  float* beta = sc   + 256;               // [2][128]
  float* ctxl = beta + 256;               // [2][128]
  float* wwl  = ctxl + 256;               // [132]
  float* fcw  = wwl  + 132;               // [256]
  float* wdb  = fcw  + 256;               // [128]
  float* yrow = wdb  + 128;               // [2][128]
  float* v2l  = yrow + 256;               // [128]  -2*v_d
  float* scal = v2l  + 128;               // [8]
  float* act2 = scal + 8;                 // [2][512] gate partials / activations
  float* part = act2 + 1024;              // [2][8][128]
  unsigned int* hc2 = (unsigned int*)(part + 2048);  // [2][128]: per batch h-pairs[64], c-pairs[64]
  unsigned int* bt2 = hc2 + 256;                     // [2][64] beta f16-pairs

  const int tid = threadIdx.x;
  const int g   = tid & 511;
  const int dh  = tid >> 9;
  const int e1  = tid & 127;
  const int ck  = (tid >> 7) & 7;

  // ---- persistent per-thread weights, f16 pairs (50 values, pinned) ----
  unsigned int whh2[32];
#pragma unroll
  for (int p = 0; p < 32; ++p)
    whh2[p] = packf16(Whh[g * 128 + dh * 64 + 2 * p], Whh[g * 128 + dh * 64 + 2 * p + 1]);
  unsigned int wdr2[16];
#pragma unroll
  for (int j = 0; j < 16; ++j)
    wdr2[j] = packf16(Wdhs[e1 * 256 + ck * 32 + 2 * j], Wdhs[e1 * 256 + ck * 32 + 2 * j + 1]);
  float bihh = bih[g] + bhh[g];
  float wihr = Wih[g];
#pragma unroll
  for (int p = 0; p < 32; ++p) asm volatile("" : "+v"(whh2[p]));
#pragma unroll
  for (int j = 0; j < 16; ++j) asm volatile("" : "+v"(wdr2[j]));
  asm volatile("" : "+v"(bihh));
  asm volatile("" : "+v"(wihr));

  // ---- one-time constants ----
  if (tid < 129) wwl[tid] = ww[tid];
  if (tid == 0)  wwl[129] = wb[0];
  if (tid < 256) fcw[tid] = fcww[tid];
  if (tid < 128) { wdb[tid] = Wdhsb[tid]; v2l[tid] = -2.0f * vdw[tid]; }

  for (int bi = 0; bi < kBPW / 2; ++bi) {
    const int b0 = blockIdx.x * kBPW + bi * 2;
    const float* Xp0 = Xg + (size_t)b0 * (kT * kE);
    const float* Xp1 = Xg + (size_t)(b0 + 1) * (kT * kE);
    float creg = 0.0f, ghsum0 = 0.0f, ghsum1 = 0.0f;
    __syncthreads();   // previous pair done with LDS

    // (a) stage Udw as f16 pairs into xbT scratch area; yrow; zero state
    {
      unsigned int* udw2 = xbT;
      const int r = tid >> 3, c2 = (tid & 7) * 2;
#pragma unroll
      for (int ch = 0; ch < 2; ++ch) {
        const int c = c2 + ch;
        uint4 st;
        st.x = packf16(Udw[r * kE + c * 8 + 0], Udw[r * kE + c * 8 + 1]);
        st.y = packf16(Udw[r * kE + c * 8 + 2], Udw[r * kE + c * 8 + 3]);
        st.z = packf16(Udw[r * kE + c * 8 + 4], Udw[r * kE + c * 8 + 5]);
        st.w = packf16(Udw[r * kE + c * 8 + 6], Udw[r * kE + c * 8 + 7]);
        *(uint4*)&udw2[r * 64 + ((c ^ ((r >> 4) & 7)) << 2)] = st;
      }
    }
    if (tid < 256) {
      const int j = tid >> 7, l = tid & 127;
      yrow[j * 128 + l] = (l < kT) ? yh[(size_t)(b0 + j) * kT + l] : 0.0f;
      hc2[tid] = 0u;
    }
    __syncthreads();

    // (b) U2 = K2*(X @ Udw^T + Udb) for both batches, from LDS-staged Udw
    {
      const unsigned int* udw2 = xbT;
      const int ts = tid >> 3, q8 = tid & 7, eb = q8 * 16;
      if (ts < kT) {
        for (int j = 0; j < 2; ++j) {
          const float* Xrow = (j ? Xp1 : Xp0) + ts * kE;
          float acc[16];
#pragma unroll
          for (int jj = 0; jj < 16; ++jj) acc[jj] = 0.0f;
#pragma unroll 4
          for (int k4 = 0; k4 < 16; ++k4) {
            const float4 xa = *(const float4*)&Xrow[k4 * 8];
            const float4 xb4 = *(const float4*)&Xrow[k4 * 8 + 4];
            const unsigned int xp0 = packf16(xa.x, xa.y), xp1v = packf16(xa.z, xa.w);
            const unsigned int xp2 = packf16(xb4.x, xb4.y), xp3 = packf16(xb4.z, xb4.w);
#pragma unroll
            for (int jj = 0; jj < 16; ++jj) {
              const int rr = eb + jj;
              const uint4 wq = *(const uint4*)&udw2[rr * 64 + ((k4 ^ ((rr >> 4) & 7)) << 2)];
              float a = acc[jj];
              a = fdot2f(xp0, wq.x, a);
              a = fdot2f(xp1v, wq.y, a);
              a = fdot2f(xp2, wq.z, a);
              a = fdot2f(xp3, wq.w, a);
              acc[jj] = a;
            }
          }
#pragma unroll
          for (int ch = 0; ch < 2; ++ch) {
            const int c = q8 * 2 + ch, ebb = eb + ch * 8;
            uint4 st;
            st.x = packf16(kK2 * (acc[ch*8+0] + Udb[ebb+0]), kK2 * (acc[ch*8+1] + Udb[ebb+1]));
            st.y = packf16(kK2 * (acc[ch*8+2] + Udb[ebb+2]), kK2 * (acc[ch*8+3] + Udb[ebb+3]));
            st.z = packf16(kK2 * (acc[ch*8+4] + Udb[ebb+4]), kK2 * (acc[ch*8+5] + Udb[ebb+5]));
            st.w = packf16(kK2 * (acc[ch*8+6] + Udb[ebb+6]), kK2 * (acc[ch*8+7] + Udb[ebb+7]));
            *(uint4*)&u2u[(j * 128 + ts) * 64 + ((c ^ (ts & 15)) << 2)] = st;
          }
        }
      }
    }
    __syncthreads();

    // (c) stage xbT f16 t-pairs (overwrites Udw scratch)
    {
      const int j = tid >> 9, e = tid & 127, sub = (tid >> 7) & 3;
      const float* Xbj = j ? Xp1 : Xp0;
      for (int t2 = sub; t2 < 64; t2 += 4) {
        const float a  = Xbj[(2 * t2) * kE + e];
        const float bq = (t2 == 63) ? 0.0f : Xbj[(2 * t2 + 1) * kE + e];
        xbT[(j * 128 + e) * 64 + (t2 ^ (e & 63))] = packf16(a, bq);
      }
    }
    __syncthreads();

    // ================= 127 recurrent steps (2 batches per step) =================
    for (int s = 0; s < kT; ++s) {
      // P1: gates (both batches, same pinned weights) + proj partials
      float gacc0 = 0.0f, gacc1 = 0.0f;
#pragma unroll
      for (int q = 0; q < 8; ++q) {
        const uint4 ha = *(const uint4*)&hc2[dh * 32 + q * 4];
        const uint4 hb = *(const uint4*)&hc2[128 + dh * 32 + q * 4];
        gacc0 = fdot2f(whh2[q*4+0], ha.x, gacc0);
        gacc0 = fdot2f(whh2[q*4+1], ha.y, gacc0);
        gacc0 = fdot2f(whh2[q*4+2], ha.z, gacc0);
        gacc0 = fdot2f(whh2[q*4+3], ha.w, gacc0);
        gacc1 = fdot2f(whh2[q*4+0], hb.x, gacc1);
        gacc1 = fdot2f(whh2[q*4+1], hb.y, gacc1);
        gacc1 = fdot2f(whh2[q*4+2], hb.z, gacc1);
        gacc1 = fdot2f(whh2[q*4+3], hb.w, gacc1);
      }
      float pacc0 = 0.0f, pacc1 = 0.0f;
#pragma unroll
      for (int q = 0; q < 4; ++q) {
        const uint4 pa_ = *(const uint4*)&hc2[ck * 16 + q * 4];
        const uint4 pb_ = *(const uint4*)&hc2[128 + ck * 16 + q * 4];
        pacc0 = fdot2f(wdr2[q*4+0], pa_.x, pacc0);
        pacc0 = fdot2f(wdr2[q*4+1], pa_.y, pacc0);
        pacc0 = fdot2f(wdr2[q*4+2], pa_.z, pacc0);
        pacc0 = fdot2f(wdr2[q*4+3], pa_.w, pacc0);
        pacc1 = fdot2f(wdr2[q*4+0], pb_.x, pacc1);
        pacc1 = fdot2f(wdr2[q*4+1], pb_.y, pacc1);
        pacc1 = fdot2f(wdr2[q*4+2], pb_.z, pacc1);
        pacc1 = fdot2f(wdr2[q*4+3], pb_.w, pacc1);
      }
      part[ck * 128 + e1]        = pacc0;
      part[1024 + ck * 128 + e1] = pacc1;
      if (dh) { act2[g] = gacc0; act2[512 + g] = gacc1; }
      __syncthreads();  // B1

      // P2: combine gate halves; reduce proj -> p2 (prescaled by K2)
      if (tid < 512) {
        ghsum0 = gacc0 + act2[g] + bihh;
        ghsum1 = gacc1 + act2[512 + g] + bihh;
      }
      if (tid < 256) {
        const int j = tid >> 7, e = tid & 127;
        float ps = wdb[e];
#pragma unroll
        for (int k = 0; k < 8; ++k) ps += part[j * 1024 + k * 128 + e];
        p2[j * 128 + e] = kK2 * ps;
      }
      __syncthreads();  // B2

      // P3: scores (4 lanes per (j,t) row, 32 e each); softmax-shift-invariant
      {
        const int r = tid >> 2, j = r >> 7, t = r & 127, q = tid & 3;
        if (t < kT) {
          const unsigned int* urow = &u2u[(j * 128 + t) * 64];
          const float* p2j = &p2[j * 128];
          float sacc = 0.0f;
#pragma unroll
          for (int i = 0; i < 4; ++i) {
            const int c = q * 4 + i;
            const uint4 uq = *(const uint4*)&urow[(c ^ (t & 15)) << 2];
            const int e0 = c * 8;
            const float4 pa = *(const float4*)&p2j[e0];
            const float4 pb = *(const float4*)&p2j[e0 + 4];
            const float4 va = *(const float4*)&v2l[e0];
            const float4 vb = *(const float4*)&v2l[e0 + 4];
            sacc += va.x * RCPF(1.0f + EXP2F(lo16f(uq.x) + pa.x));
            sacc += va.y * RCPF(1.0f + EXP2F(hi16f(uq.x) + pa.y));
            sacc += va.z * RCPF(1.0f + EXP2F(lo16f(uq.y) + pa.z));
            sacc += va.w * RCPF(1.0f + EXP2F(hi16f(uq.y) + pa.w));
            sacc += vb.x * RCPF(1.0f + EXP2F(lo16f(uq.z) + pb.x));
            sacc += vb.y * RCPF(1.0f + EXP2F(hi16f(uq.z) + pb.y));
            sacc += vb.z * RCPF(1.0f + EXP2F(lo16f(uq.w) + pb.z));
            sacc += vb.w * RCPF(1.0f + EXP2F(hi16f(uq.w) + pb.w));
          }
          sacc += __shfl_xor(sacc, 1, 64);
          sacc += __shfl_xor(sacc, 2, 64);
          if (q == 0) sc[j * 128 + t] = sacc;
        }
      }
      __syncthreads();  // B3

      // P4: softmax per batch (wave 0 -> batch 0, wave 1 -> batch 1); no max pass
      if (tid < 128) {
        const int j = tid >> 6, l = tid & 63;
        const float e0  = EXP2F(sc[j * 128 + l] * kLog2e);
        const float e1x = (l + 64 < kT) ? EXP2F(sc[j * 128 + l + 64] * kLog2e) : 0.0f;
        float sum = e0 + e1x;
        sum = redsum64(sum);
        const float rs = RCPF(sum);
        const float b0v = e0 * rs, b1v = e1x * rs;
        beta[j * 128 + l]      = b0v;
        beta[j * 128 + l + 64] = b1v;        // beta[127] = 0
        const float o0 = __shfl_xor(b0v, 1, 64);
        const float o1 = __shfl_xor(b1v, 1, 64);
        if ((l & 1) == 0) {
          bt2[j * 64 + (l >> 1)]      = packf16(b0v, o0);
          bt2[j * 64 + 32 + (l >> 1)] = packf16(b1v, o1);
        }
      }
      __syncthreads();  // B4

      // P5: ctx partials (512 lanes per batch; 16 t-pair dots each)
      {
        const int j = tid >> 9, e = tid & 127, kc = (tid >> 7) & 3, em = e & 63;
        const unsigned int* xrow = &xbT[(j * 128 + e) * 64];
        const unsigned int* b2 = &bt2[j * 64];
        float cacc = 0.0f;
#pragma unroll
        for (int q = 0; q < 16; ++q) {
          const int t2 = kc * 16 + q;
          cacc = fdot2f(b2[t2], xrow[t2 ^ em], cacc);
        }
        part[j * 1024 + kc * 128 + e] = cacc;
      }
      __syncthreads();  // B5

      // P6: ctx reduce (lanes 0-255) || y_tilde (waves 8-9)
      if (tid < 256) {
        const int j = tid >> 7, e = tid & 127;
        const float cs = part[j*1024 + e] + part[j*1024 + 128 + e]
                       + part[j*1024 + 256 + e] + part[j*1024 + 384 + e];
        ctxl[j * 128 + e] = cs;
      }
      if (tid >= 512 && tid < 640) {
        const int j = (tid >> 6) & 1, l = tid & 63;
        float ya = 0.0f;
#pragma unroll
        for (int k = 0; k < 4; ++k)
          ya += part[j*1024 + k*128 + l] * wwl[l] + part[j*1024 + k*128 + l + 64] * wwl[l + 64];
        ya = redsum64(ya);
        if (l == 0) scal[j] = ya + wwl[128] * yrow[j * 128 + s] + wwl[129];
      }
      __syncthreads();  // B6

      // P7: gate nonlinearities for both batches (wave-uniform role)
      if (tid < 512) {
        const int role = tid >> 7;
        const float ga0 = ghsum0 + scal[0] * wihr;
        const float ga1 = ghsum1 + scal[1] * wihr;
        float a0, a1;
        if (role == 2) {
          a0 = 1.0f - 2.0f * RCPF(1.0f + EXP2F(ga0 * kK2));
          a1 = 1.0f - 2.0f * RCPF(1.0f + EXP2F(ga1 * kK2));
        } else {
          a0 = RCPF(1.0f + EXP2F(-ga0 * kLog2e));
          a1 = RCPF(1.0f + EXP2F(-ga1 * kLog2e));
        }
        act2[tid] = a0;
        act2[512 + tid] = a1;
      }
      __syncthreads();  // B7

      // P8: LSTM state update (lanes 0-255; 128 per batch)
      if (tid < 256) {
        const int j = tid >> 7, d = tid & 127;
        const float i_g = act2[j*512 + d];
        const float f_g = act2[j*512 + 128 + d];
        const float gg  = act2[j*512 + 256 + d];
        const float o_g = act2[j*512 + 384 + d];
        const float cn  = f_g * creg + i_g * gg;
        const float th  = 1.0f - 2.0f * RCPF(1.0f + EXP2F(cn * kK2));
        const float hn  = o_g * th;
        creg = cn;
        hl[j * 128 + d] = hn;
        const float ho = __shfl_xor(hn, 1, 64);
        const float co = __shfl_xor(cn, 1, 64);
        if ((d & 1) == 0) {
          hc2[j * 128 + (d >> 1)]      = packf16(hn, ho);
          hc2[j * 128 + 64 + (d >> 1)] = packf16(cn, co);
        }
      }
      __syncthreads();  // B8
    }  // steps

    // ---- final ctx in fp32 from global X + fc ----
    {
      const int j = tid >> 9, e = tid & 127, kc = (tid >> 7) & 3;
      const float* Xbj = j ? Xp1 : Xp0;
      float cacc = 0.0f;
#pragma unroll
      for (int q = 0; q < 32; ++q) {
        const int tt = kc * 32 + q;
        if (tt < kT) cacc += beta[j * 128 + tt] * Xbj[tt * kE + e];
      }
      part[j * 1024 + kc * 128 + e] = cacc;
    }
    __syncthreads();
    if (tid < 256) {
      const int j = tid >> 7, e = tid & 127;
      ctxl[j * 128 + e] = part[j*1024 + e] + part[j*1024 + 128 + e]
                        + part[j*1024 + 256 + e] + part[j*1024 + 384 + e];
    }
    __syncthreads();
    if (tid < 128) {
      const int j = tid >> 6, l = tid & 63;
      float a = hl[j*128 + l] * fcw[l] + hl[j*128 + l + 64] * fcw[l + 64]
              + ctxl[j*128 + l] * fcw[128 + l] + ctxl[j*128 + l + 64] * fcw[192 + l];
      a = redsum64(a);
      if (l == 0) out[b0 + j] = a + fcb[0];
    }
  }  // pair loop
}
}  // namespace

extern "C" void kernel_launch(void* const* d_in, const int* in_sizes, int n_in,
                              void* d_out, int out_size, void* d_ws, size_t ws_size,
                              hipStream_t stream) {
  (void)in_sizes; (void)n_in; (void)d_ws; (void)ws_size; (void)out_size;
  const float* Xg    = (const float*)d_in[0];
  const float* yh    = (const float*)d_in[1];
  const float* vdw   = (const float*)d_in[2];
  const float* vdb   = (const float*)d_in[3];
  const float* Wdhs  = (const float*)d_in[4];
  const float* Wdhsb = (const float*)d_in[5];
  const float* Udw   = (const float*)d_in[6];
  const float* Udb   = (const float*)d_in[7];
  const float* ww    = (const float*)d_in[8];
  const float* wb    = (const float*)d_in[9];
  const float* Wih   = (const float*)d_in[10];
  const float* Whh   = (const float*)d_in[11];
  const float* bih   = (const float*)d_in[12];
  const float* bhh   = (const float*)d_in[13];
  const float* fcww  = (const float*)d_in[14];
  const float* fcb   = (const float*)d_in[15];
  float* out = (float*)d_out;

  hipFuncSetAttribute((const void*)decoder_kernel,
                      hipFuncAttributeMaxDynamicSharedMemorySize, kSmemBytes);
  decoder_kernel<<<dim3(kNWG), dim3(1024), kSmemBytes, stream>>>(
      Xg, yh, vdw, vdb, Wdhs, Wdhsb, Udw, Udb, ww, wb,
      Wih, Whh, bih, bhh, fcww, fcb, out);
}